// Round 7
// baseline (877.601 us; speedup 1.0000x reference)
//
#include <hip/hip_runtime.h>
#include <math.h>

#define BB 16
#define NN 4096
#define DD 64
#define OO 12
#define SS 32
#define MM 12
#define AA 32

// out layout: H_time [B,O,N,D] | attn [B,O,N,M] | gate [B,O,M]
// 8 lanes per row, 32 rows per 256-thread block -> 2048 blocks, 32 waves/CU at <=64 VGPR.
__global__ __launch_bounds__(256, 8) void stta_kernel(
    const float* __restrict__ H, const float* __restrict__ ts_out,
    const float* __restrict__ step_emb, const float* __restrict__ key_emb,
    const float* __restrict__ val_emb, const float* __restrict__ Wk,
    const float* __restrict__ Wg, const float* __restrict__ bgp,
    const float* __restrict__ Wq, const float* __restrict__ bq,
    float* __restrict__ out)
{
    const int b = blockIdx.y;
    const int n0 = blockIdx.x * 32;    // block covers 32 rows
    const int tid = threadIdx.x;

    __shared__ __align__(16) float s_ke[MM * AA];       // key_emb[m][a]
    __shared__ __align__(16) float s_ve[MM * DD];       // val_emb[m][d]
    __shared__ __align__(16) float s_wk0[32];
    __shared__ __align__(16) float s_wk1[32];
    __shared__ __align__(16) float s_tokS[OO * MM];
    __shared__ __align__(16) float s_tokC[OO * MM];
    __shared__ __align__(16) float s_gate[OO * MM];
    __shared__ __align__(16) float s_qs[OO * AA];       // qs[o][a]
    __shared__ __align__(16) float s_c2[OO * MM];       // scale * (qs[o] . key[o,m])
    __shared__ __align__(16) float s_pm[14 * 64];       // rows 0..11 = scale*(ke[m]@Wq),
                                                        // 12 = scale*(wk0@Wq), 13 = scale*(wk1@Wq)

    float* outH    = out;
    float* outAttn = out + (size_t)BB * OO * NN * DD;
    float* outGate = outAttn + (size_t)BB * OO * NN * MM;

    const float scale = 0.17677669529663687f; // 1/sqrt(32)

    // ---- staging ----
    {
        float4* dst = reinterpret_cast<float4*>(s_ke);
        const float4* src = reinterpret_cast<const float4*>(key_emb);
        for (int i = tid; i < (MM * AA) / 4; i += 256) dst[i] = src[i];
    }
    {
        float4* dst = reinterpret_cast<float4*>(s_ve);
        const float4* src = reinterpret_cast<const float4*>(val_emb);
        for (int i = tid; i < (MM * DD) / 4; i += 256) dst[i] = src[i];
    }
    if (tid < 32) { s_wk0[tid] = Wk[tid * 2]; s_wk1[tid] = Wk[tid * 2 + 1]; }

    const float wg0 = Wg[0], wg1 = Wg[1], bg0 = bgp[0];
    for (int i = tid; i < OO * MM; i += 256) {
        int o = i / MM, m = i - o * MM;
        float phase = ts_out[(b * OO + o) * 2 + (m < 8 ? 0 : 1)];
        float k = (m < 8) ? (float)(m + 1) : (float)(m - 7);
        float ang = 6.283185307179586f * phase * k;
        float sv = sinf(ang), cv = cosf(ang);
        s_tokS[i] = sv; s_tokC[i] = cv;
        float gv = tanhf(sv * wg0 + cv * wg1 + bg0);
        s_gate[i] = gv;
        if (blockIdx.x == 0) outGate[(b * OO + o) * MM + m] = gv;
    }
    for (int e = tid; e < OO * AA; e += 256) {
        int o = e >> 5, a = e & 31;
        float acc = bq[a];
        const float* se = step_emb + (b * OO + o) * SS;
        const float* wq = Wq + a * 96 + 64;
        #pragma unroll
        for (int s = 0; s < SS; s++) acc += se[s] * wq[s];
        s_qs[e] = acc;
    }
    __syncthreads();

    // ---- c2[o][m] = scale * (qs[o] . key[o,m]) ----
    for (int i = tid; i < OO * MM; i += 256) {
        int o = i / MM, m = i - o * MM;
        float S = s_tokS[i], C = s_tokC[i];
        float acc = 0.f;
        const float* qs = s_qs + o * 32;
        const float* ke = s_ke + m * 32;
        #pragma unroll
        for (int a = 0; a < 32; a++)
            acc += qs[a] * (S * s_wk0[a] + C * s_wk1[a] + ke[a]);
        s_c2[i] = acc * scale;
    }
    // ---- fold projections straight from global Wq (L2-hot, coalesced over d) ----
    for (int i = tid; i < 14 * 64; i += 256) {
        int j = i >> 6, d = i & 63;
        const float* coef = (j < 12) ? (s_ke + j * 32) : ((j == 12) ? s_wk0 : s_wk1);
        float acc = 0.f;
        #pragma unroll
        for (int a = 0; a < 32; a++) acc += coef[a] * Wq[a * 96 + d];
        s_pm[i] = acc * scale;
    }
    __syncthreads();

    const int nl = tid >> 3, g = tid & 7;
    const int n = n0 + nl;

    // ---- load my 8 H values: chunks g and g+8 (full 128B segments per row) ----
    const float4* hrow = reinterpret_cast<const float4*>(H + ((size_t)b * NN + n) * DD);
    float4 h0 = hrow[g];
    float4 h1 = hrow[g + 8];

    // ---- f[j] = h . pm[j]; partial over my 8 d's, butterfly over 8-lane group ----
    float f[14];
    #pragma unroll
    for (int j = 0; j < 14; j++) {
        const float4* pm = reinterpret_cast<const float4*>(s_pm + j * 64);
        float4 w0 = pm[g], w1 = pm[g + 8];
        f[j] = h0.x*w0.x + h0.y*w0.y + h0.z*w0.z + h0.w*w0.w
             + h1.x*w1.x + h1.y*w1.y + h1.z*w1.z + h1.w*w1.w;
    }
    #pragma unroll
    for (int j = 0; j < 14; j++) f[j] += __shfl_xor(f[j], 1);
    #pragma unroll
    for (int j = 0; j < 14; j++) f[j] += __shfl_xor(f[j], 2);
    #pragma unroll
    for (int j = 0; j < 14; j++) f[j] += __shfl_xor(f[j], 4);

    const float4* ve4 = reinterpret_cast<const float4*>(s_ve);

    // ---- main loop: o in PAIRS so each s_ve read feeds two o's ----
    for (int op = 0; op < OO; op += 2) {
        const float4* tS  = reinterpret_cast<const float4*>(s_tokS + op * 12);
        const float4* tC  = reinterpret_cast<const float4*>(s_tokC + op * 12);
        const float4* tc2 = reinterpret_cast<const float4*>(s_c2   + op * 12);
        const float4* tgt = reinterpret_cast<const float4*>(s_gate + op * 12);

        float lg0[12], lg1[12];
        #pragma unroll
        for (int q = 0; q < 3; q++) {
            float4 S = tS[q], C = tC[q], c = tc2[q];
            lg0[q*4+0] = S.x*f[12] + C.x*f[13] + f[q*4+0] + c.x;
            lg0[q*4+1] = S.y*f[12] + C.y*f[13] + f[q*4+1] + c.y;
            lg0[q*4+2] = S.z*f[12] + C.z*f[13] + f[q*4+2] + c.z;
            lg0[q*4+3] = S.w*f[12] + C.w*f[13] + f[q*4+3] + c.w;
        }
        #pragma unroll
        for (int q = 0; q < 3; q++) {
            float4 S = tS[3+q], C = tC[3+q], c = tc2[3+q];
            lg1[q*4+0] = S.x*f[12] + C.x*f[13] + f[q*4+0] + c.x;
            lg1[q*4+1] = S.y*f[12] + C.y*f[13] + f[q*4+1] + c.y;
            lg1[q*4+2] = S.z*f[12] + C.z*f[13] + f[q*4+2] + c.z;
            lg1[q*4+3] = S.w*f[12] + C.w*f[13] + f[q*4+3] + c.w;
        }

        float mx0 = -1e30f, mx1 = -1e30f;
        #pragma unroll
        for (int m = 0; m < 12; m++) { mx0 = fmaxf(mx0, lg0[m]); mx1 = fmaxf(mx1, lg1[m]); }
        float sum0 = 0.f, sum1 = 0.f;
        #pragma unroll
        for (int m = 0; m < 12; m++) {
            lg0[m] = __expf(lg0[m] - mx0); sum0 += lg0[m];
            lg1[m] = __expf(lg1[m] - mx1); sum1 += lg1[m];
        }
        float inv0 = 1.f / sum0, inv1 = 1.f / sum1;
        #pragma unroll
        for (int m = 0; m < 12; m++) { lg0[m] *= inv0; lg1[m] *= inv1; }

        // attn writes [B,O,N,M] — lanes g=0..2 each store one float4 per o
        size_t abase0 = ((size_t)(b * OO + op) * NN + n) * MM;
        size_t abase1 = abase0 + (size_t)NN * MM;
        if (g == 0) {
            *reinterpret_cast<float4*>(outAttn + abase0) =
                make_float4(lg0[0], lg0[1], lg0[2], lg0[3]);
            *reinterpret_cast<float4*>(outAttn + abase1) =
                make_float4(lg1[0], lg1[1], lg1[2], lg1[3]);
        } else if (g == 1) {
            *reinterpret_cast<float4*>(outAttn + abase0 + 4) =
                make_float4(lg0[4], lg0[5], lg0[6], lg0[7]);
            *reinterpret_cast<float4*>(outAttn + abase1 + 4) =
                make_float4(lg1[4], lg1[5], lg1[6], lg1[7]);
        } else if (g == 2) {
            *reinterpret_cast<float4*>(outAttn + abase0 + 8) =
                make_float4(lg0[8], lg0[9], lg0[10], lg0[11]);
            *reinterpret_cast<float4*>(outAttn + abase1 + 8) =
                make_float4(lg1[8], lg1[9], lg1[10], lg1[11]);
        }

        // fold gate into attn weights (in place)
        #pragma unroll
        for (int q = 0; q < 3; q++) {
            float4 g0 = tgt[q], g1 = tgt[3+q];
            lg0[q*4+0] *= g0.x; lg0[q*4+1] *= g0.y; lg0[q*4+2] *= g0.z; lg0[q*4+3] *= g0.w;
            lg1[q*4+0] *= g1.x; lg1[q*4+1] *= g1.y; lg1[q*4+2] *= g1.z; lg1[q*4+3] *= g1.w;
        }

        // delta + H_time: one ve4 read feeds 2 o's; chunks g and g+8
        size_t hbase = ((size_t)(b * OO + op) * NN + n) * DD;
        float4* outp0 = reinterpret_cast<float4*>(outH + hbase);
        float4* outp1 = reinterpret_cast<float4*>(outH + hbase + (size_t)NN * DD);
        #pragma unroll
        for (int jj = 0; jj < 2; jj++) {
            const float4 hh = (jj == 0) ? h0 : h1;
            const int slot = g + 8 * jj;
            float ax0=0.f, ay0=0.f, az0=0.f, aw0=0.f;
            float ax1=0.f, ay1=0.f, az1=0.f, aw1=0.f;
            #pragma unroll
            for (int m = 0; m < 12; m++) {
                float4 vv = ve4[m * 16 + slot];
                ax0 += lg0[m]*vv.x; ay0 += lg0[m]*vv.y;
                az0 += lg0[m]*vv.z; aw0 += lg0[m]*vv.w;
                ax1 += lg1[m]*vv.x; ay1 += lg1[m]*vv.y;
                az1 += lg1[m]*vv.z; aw1 += lg1[m]*vv.w;
            }
            outp0[slot] = make_float4(hh.x + 0.1f*ax0, hh.y + 0.1f*ay0,
                                      hh.z + 0.1f*az0, hh.w + 0.1f*aw0);
            outp1[slot] = make_float4(hh.x + 0.1f*ax1, hh.y + 0.1f*ay1,
                                      hh.z + 0.1f*az1, hh.w + 0.1f*aw1);
        }
    }
}

extern "C" void kernel_launch(void* const* d_in, const int* in_sizes, int n_in,
                              void* d_out, int out_size, void* d_ws, size_t ws_size,
                              hipStream_t stream) {
    const float* H        = (const float*)d_in[0];
    const float* ts_out   = (const float*)d_in[1];
    const float* step_emb = (const float*)d_in[2];
    const float* key_emb  = (const float*)d_in[3];
    const float* val_emb  = (const float*)d_in[4];
    const float* Wk       = (const float*)d_in[5];
    const float* Wg       = (const float*)d_in[6];
    const float* bg       = (const float*)d_in[7];
    const float* Wq       = (const float*)d_in[8];
    const float* bq       = (const float*)d_in[9];
    float* outp = (float*)d_out;

    dim3 grid(NN / 32, BB);
    stta_kernel<<<grid, 256, 0, stream>>>(H, ts_out, step_emb, key_emb, val_emb,
                                          Wk, Wg, bg, Wq, bq, outp);
}

// Round 8
// 465.821 us; speedup vs baseline: 1.8840x; 1.8840x over previous
//
#include <hip/hip_runtime.h>
#include <math.h>

#define BB 16
#define NN 4096
#define DD 64
#define OO 12
#define SS 32
#define MM 12
#define AA 32

// out layout: H_time [B,O,N,D] | attn [B,O,N,M] | gate [B,O,M]
__global__ __launch_bounds__(256, 4) void stta_kernel(
    const float* __restrict__ H, const float* __restrict__ ts_out,
    const float* __restrict__ step_emb, const float* __restrict__ key_emb,
    const float* __restrict__ val_emb, const float* __restrict__ Wk,
    const float* __restrict__ Wg, const float* __restrict__ bgp,
    const float* __restrict__ Wq, const float* __restrict__ bq,
    float* __restrict__ out)
{
    const int b = blockIdx.y;
    const int n0 = blockIdx.x * 64;
    const int tid = threadIdx.x;

    __shared__ __align__(16) float s_wq[32 * 64];       // Wq[a][d], d<64
    __shared__ __align__(16) float s_ke[MM * AA];       // key_emb[m][a]
    __shared__ __align__(16) float s_ve[MM * DD];       // val_emb[m][d]
    __shared__ __align__(16) float s_wk0[32];
    __shared__ __align__(16) float s_wk1[32];
    __shared__ __align__(16) float s_tokS[OO * MM];
    __shared__ __align__(16) float s_tokC[OO * MM];
    __shared__ __align__(16) float s_gate[OO * MM];
    __shared__ __align__(16) float s_qs[OO * AA];       // qs[o][a]
    __shared__ __align__(16) float s_c2[OO * MM];       // scale * (qs[o] . key[o,m])
    __shared__ __align__(16) float s_pm[14 * 64];       // rows 0..11 = scale*(ke[m]@Wq),
                                                        // 12 = scale*(wk0@Wq), 13 = scale*(wk1@Wq)

    float* outH    = out;
    float* outAttn = out + (size_t)BB * OO * NN * DD;
    float* outGate = outAttn + (size_t)BB * OO * NN * MM;

    const float scale = 0.17677669529663687f; // 1/sqrt(32)

    // ---- staging (vectorized float4 copies) ----
    {
        float4* dst = reinterpret_cast<float4*>(s_wq);
        for (int i = tid; i < 512; i += 256) {
            int a = i >> 4, dq = i & 15;
            dst[i] = reinterpret_cast<const float4*>(Wq + a * 96)[dq];
        }
    }
    {
        float4* dst = reinterpret_cast<float4*>(s_ke);
        const float4* src = reinterpret_cast<const float4*>(key_emb);
        for (int i = tid; i < (MM * AA) / 4; i += 256) dst[i] = src[i];
    }
    {
        float4* dst = reinterpret_cast<float4*>(s_ve);
        const float4* src = reinterpret_cast<const float4*>(val_emb);
        for (int i = tid; i < (MM * DD) / 4; i += 256) dst[i] = src[i];
    }
    if (tid < 32) { s_wk0[tid] = Wk[tid * 2]; s_wk1[tid] = Wk[tid * 2 + 1]; }

    const float wg0 = Wg[0], wg1 = Wg[1], bg0 = bgp[0];
    for (int i = tid; i < OO * MM; i += 256) {
        int o = i / MM, m = i - o * MM;
        float phase = ts_out[(b * OO + o) * 2 + (m < 8 ? 0 : 1)];
        float k = (m < 8) ? (float)(m + 1) : (float)(m - 7);
        float ang = 6.283185307179586f * phase * k;
        float sv = sinf(ang), cv = cosf(ang);
        s_tokS[i] = sv; s_tokC[i] = cv;
        float gv = tanhf(sv * wg0 + cv * wg1 + bg0);
        s_gate[i] = gv;
        if (blockIdx.x == 0) outGate[(b * OO + o) * MM + m] = gv;
    }
    for (int e = tid; e < OO * AA; e += 256) {
        int o = e >> 5, a = e & 31;
        float acc = bq[a];
        const float* se = step_emb + (b * OO + o) * SS;
        const float* wq = Wq + a * 96 + 64;
        #pragma unroll
        for (int s = 0; s < SS; s++) acc += se[s] * wq[s];
        s_qs[e] = acc;
    }
    __syncthreads();

    // ---- c2[o][m] = scale * (qs[o] . key[o,m]) ----
    for (int i = tid; i < OO * MM; i += 256) {
        int o = i / MM, m = i - o * MM;
        float S = s_tokS[i], C = s_tokC[i];
        float acc = 0.f;
        const float* qs = s_qs + o * 32;
        const float* ke = s_ke + m * 32;
        #pragma unroll
        for (int a = 0; a < 32; a++)
            acc += qs[a] * (S * s_wk0[a] + C * s_wk1[a] + ke[a]);
        s_c2[i] = acc * scale;
    }
    // ---- fold projections: s_pm[j][d] so that f[j] = h . pm[j] ----
    for (int i = tid; i < 14 * 64; i += 256) {
        int j = i >> 6, d = i & 63;
        const float* coef = (j < 12) ? (s_ke + j * 32) : ((j == 12) ? s_wk0 : s_wk1);
        float acc = 0.f;
        #pragma unroll
        for (int a = 0; a < 32; a++) acc += coef[a] * s_wq[a * 64 + d];
        s_pm[i] = acc * scale;
    }
    __syncthreads();

    const int nl = tid >> 2, g = tid & 3;
    const int n = n0 + nl;

    // ---- load my 16 H values, chunk-interleaved (slots g, g+4, g+8, g+12) ----
    const float4* hrow = reinterpret_cast<const float4*>(H + ((size_t)b * NN + n) * DD);
    float h[16];
    #pragma unroll
    for (int jj = 0; jj < 4; jj++) {
        float4 v = hrow[g + 4 * jj];
        h[jj*4+0] = v.x; h[jj*4+1] = v.y; h[jj*4+2] = v.z; h[jj*4+3] = v.w;
    }

    // ---- f[j] = h . pm[j], partial over my 16 d's, butterfly over 4-lane group ----
    float f[14];
    #pragma unroll
    for (int j = 0; j < 14; j++) {
        const float4* pm = reinterpret_cast<const float4*>(s_pm + j * 64);
        float acc = 0.f;
        #pragma unroll
        for (int jj = 0; jj < 4; jj++) {
            float4 w = pm[g + 4 * jj];
            acc += h[jj*4+0]*w.x + h[jj*4+1]*w.y + h[jj*4+2]*w.z + h[jj*4+3]*w.w;
        }
        f[j] = acc;
    }
    #pragma unroll
    for (int j = 0; j < 14; j++) f[j] += __shfl_xor(f[j], 1);
    #pragma unroll
    for (int j = 0; j < 14; j++) f[j] += __shfl_xor(f[j], 2);

    const float uh = f[12], vh = f[13];

    const float4* ve4 = reinterpret_cast<const float4*>(s_ve);

    // ---- main loop: 4 o's per iteration -> 4 independent softmax chains (ILP),
    //      each s_ve read feeds 16 FMAs ----
    #pragma unroll 1
    for (int op = 0; op < OO; op += 4) {
        const float4* tS  = reinterpret_cast<const float4*>(s_tokS + op * 12);
        const float4* tC  = reinterpret_cast<const float4*>(s_tokC + op * 12);
        const float4* tc2 = reinterpret_cast<const float4*>(s_c2   + op * 12);
        const float4* tgt = reinterpret_cast<const float4*>(s_gate + op * 12);

        float lg[4][12];
        #pragma unroll
        for (int k = 0; k < 4; k++) {
            #pragma unroll
            for (int q = 0; q < 3; q++) {
                float4 S = tS[k*3+q], C = tC[k*3+q], c = tc2[k*3+q];
                lg[k][q*4+0] = S.x*uh + C.x*vh + f[q*4+0] + c.x;
                lg[k][q*4+1] = S.y*uh + C.y*vh + f[q*4+1] + c.y;
                lg[k][q*4+2] = S.z*uh + C.z*vh + f[q*4+2] + c.z;
                lg[k][q*4+3] = S.w*uh + C.w*vh + f[q*4+3] + c.w;
            }
        }

        // softmax: pairwise-tree max / sum, 4 independent chains
        #pragma unroll
        for (int k = 0; k < 4; k++) {
            float m0 = fmaxf(lg[k][0], lg[k][1]),  m1 = fmaxf(lg[k][2], lg[k][3]);
            float m2 = fmaxf(lg[k][4], lg[k][5]),  m3 = fmaxf(lg[k][6], lg[k][7]);
            float m4 = fmaxf(lg[k][8], lg[k][9]),  m5 = fmaxf(lg[k][10], lg[k][11]);
            float mx = fmaxf(fmaxf(fmaxf(m0, m1), fmaxf(m2, m3)), fmaxf(m4, m5));
            #pragma unroll
            for (int m = 0; m < 12; m++) lg[k][m] = __expf(lg[k][m] - mx);
            float s0 = lg[k][0] + lg[k][1],  s1 = lg[k][2] + lg[k][3];
            float s2 = lg[k][4] + lg[k][5],  s3 = lg[k][6] + lg[k][7];
            float s4 = lg[k][8] + lg[k][9],  s5 = lg[k][10] + lg[k][11];
            float sum = ((s0 + s1) + (s2 + s3)) + (s4 + s5);
            float inv = 1.f / sum;
            #pragma unroll
            for (int m = 0; m < 12; m++) lg[k][m] *= inv;
        }

        // attn writes [B,O,N,M]
        size_t abase = ((size_t)(b * OO + op) * NN + n) * MM;
        #pragma unroll
        for (int k = 0; k < 4; k++) {
            float* dst = outAttn + abase + (size_t)k * NN * MM;
            if (g == 0) {
                *reinterpret_cast<float4*>(dst) =
                    make_float4(lg[k][0], lg[k][1], lg[k][2], lg[k][3]);
            } else if (g == 1) {
                *reinterpret_cast<float4*>(dst + 4) =
                    make_float4(lg[k][4], lg[k][5], lg[k][6], lg[k][7]);
            } else if (g == 2) {
                *reinterpret_cast<float4*>(dst + 8) =
                    make_float4(lg[k][8], lg[k][9], lg[k][10], lg[k][11]);
            }
        }

        // fold gate into attn weights (in place)
        #pragma unroll
        for (int k = 0; k < 4; k++) {
            #pragma unroll
            for (int q = 0; q < 3; q++) {
                float4 gv = tgt[k*3+q];
                lg[k][q*4+0] *= gv.x; lg[k][q*4+1] *= gv.y;
                lg[k][q*4+2] *= gv.z; lg[k][q*4+3] *= gv.w;
            }
        }

        // delta + H_time: one ve4 read feeds 4 o's x 4 components
        size_t hbase = ((size_t)(b * OO + op) * NN + n) * DD;
        #pragma unroll
        for (int jj = 0; jj < 4; jj++) {
            float4 acc0 = make_float4(0.f,0.f,0.f,0.f);
            float4 acc1 = make_float4(0.f,0.f,0.f,0.f);
            float4 acc2 = make_float4(0.f,0.f,0.f,0.f);
            float4 acc3 = make_float4(0.f,0.f,0.f,0.f);
            #pragma unroll
            for (int m = 0; m < 12; m++) {
                float4 vv = ve4[m * 16 + g + 4 * jj];
                acc0.x += lg[0][m]*vv.x; acc0.y += lg[0][m]*vv.y;
                acc0.z += lg[0][m]*vv.z; acc0.w += lg[0][m]*vv.w;
                acc1.x += lg[1][m]*vv.x; acc1.y += lg[1][m]*vv.y;
                acc1.z += lg[1][m]*vv.z; acc1.w += lg[1][m]*vv.w;
                acc2.x += lg[2][m]*vv.x; acc2.y += lg[2][m]*vv.y;
                acc2.z += lg[2][m]*vv.z; acc2.w += lg[2][m]*vv.w;
                acc3.x += lg[3][m]*vv.x; acc3.y += lg[3][m]*vv.y;
                acc3.z += lg[3][m]*vv.z; acc3.w += lg[3][m]*vv.w;
            }
            const int slot = g + 4 * jj;
            const float hx = h[jj*4+0], hy = h[jj*4+1], hz = h[jj*4+2], hw = h[jj*4+3];
            reinterpret_cast<float4*>(outH + hbase)[slot] =
                make_float4(hx + 0.1f*acc0.x, hy + 0.1f*acc0.y, hz + 0.1f*acc0.z, hw + 0.1f*acc0.w);
            reinterpret_cast<float4*>(outH + hbase + (size_t)NN * DD)[slot] =
                make_float4(hx + 0.1f*acc1.x, hy + 0.1f*acc1.y, hz + 0.1f*acc1.z, hw + 0.1f*acc1.w);
            reinterpret_cast<float4*>(outH + hbase + (size_t)2 * NN * DD)[slot] =
                make_float4(hx + 0.1f*acc2.x, hy + 0.1f*acc2.y, hz + 0.1f*acc2.z, hw + 0.1f*acc2.w);
            reinterpret_cast<float4*>(outH + hbase + (size_t)3 * NN * DD)[slot] =
                make_float4(hx + 0.1f*acc3.x, hy + 0.1f*acc3.y, hz + 0.1f*acc3.z, hw + 0.1f*acc3.w);
        }
    }
}

extern "C" void kernel_launch(void* const* d_in, const int* in_sizes, int n_in,
                              void* d_out, int out_size, void* d_ws, size_t ws_size,
                              hipStream_t stream) {
    const float* H        = (const float*)d_in[0];
    const float* ts_out   = (const float*)d_in[1];
    const float* step_emb = (const float*)d_in[2];
    const float* key_emb  = (const float*)d_in[3];
    const float* val_emb  = (const float*)d_in[4];
    const float* Wk       = (const float*)d_in[5];
    const float* Wg       = (const float*)d_in[6];
    const float* bg       = (const float*)d_in[7];
    const float* Wq       = (const float*)d_in[8];
    const float* bq       = (const float*)d_in[9];
    float* outp = (float*)d_out;

    dim3 grid(NN / 64, BB);
    stta_kernel<<<grid, 256, 0, stream>>>(H, ts_out, step_emb, key_emb, val_emb,
                                          Wk, Wg, bg, Wq, bq, outp);
}